// Round 1
// baseline (436.895 us; speedup 1.0000x reference)
//
#include <hip/hip_runtime.h>

// XNOR binary linear: y = (sign(x) @ sign(W)^T) * scale
// N=262144 rows, IN=256, OUT=256, all fp32.
//
// R2 state: rocprof top-5 are all harness poison fills (1 GiB @ ~165us,
// 6.5 TB/s = achievable write ceiling). bin_linear < 163us (below top-5
// cutoff); decomposition gives ~95-100us vs an 83us mandatory-traffic
// floor (537 MB read+write @ 6.5 TB/s). Residual theory: 50% occupancy
// (launch_bounds(256,4), ~72+ VGPR) limits TLP for the mixed read+write
// stream. This round: trim to <=64 VGPR (2-deep named-register pipeline,
// flattened W[16], ballots live in SGPRs) and force 8 waves/EU ->
// 32 waves/CU, same 64 KB/CU outstanding but 2x thread-level overlap.
//
// Bit ordering: word s (s=0..3), bit l (lane) <-> element 4l+s. Same
// ordering in pack_weights (ballot) and bin_linear (ballot) -> cancels in
// the hamming distance. dot = 256 - 2*popcount(xb ^ wb), exact in fp32.

#define N_ROWS 262144
#define IN_DIM 256
#define OUT_DIM 256
#define ROWS_PER_WAVE 32

typedef unsigned long long u64;
typedef float f32x4 __attribute__((ext_vector_type(4)));

__global__ void pack_weights(const float* __restrict__ w, u64* __restrict__ wb) {
    const int o = blockIdx.x;          // output channel 0..255
    const int l = threadIdx.x;         // lane 0..63
    const float4 f = ((const float4*)(w + (size_t)o * IN_DIM))[l];
    u64 b0 = __ballot(f.x < 0.0f);
    u64 b1 = __ballot(f.y < 0.0f);
    u64 b2 = __ballot(f.z < 0.0f);
    u64 b3 = __ballot(f.w < 0.0f);
    if (l == 0) {
        wb[o * 4 + 0] = b0;
        wb[o * 4 + 1] = b1;
        wb[o * 4 + 2] = b2;
        wb[o * 4 + 3] = b3;
    }
}

__device__ __forceinline__ f32x4 row_dot(f32x4 cur, const u64* __restrict__ W, f32x4 sc) {
    // Ballot results live in SGPR pairs (wave-uniform) -> no VGPR cost;
    // v_xor takes one SGPR operand directly.
    const u64 b0 = __ballot(cur.x < 0.0f);
    const u64 b1 = __ballot(cur.y < 0.0f);
    const u64 b2 = __ballot(cur.z < 0.0f);
    const u64 b3 = __ballot(cur.w < 0.0f);
    f32x4 o4;
    {
        int h = __builtin_popcountll(b0 ^ W[0])  + __builtin_popcountll(b1 ^ W[1])
              + __builtin_popcountll(b2 ^ W[2])  + __builtin_popcountll(b3 ^ W[3]);
        o4.x = (float)(IN_DIM - 2 * h) * sc.x;
    }
    {
        int h = __builtin_popcountll(b0 ^ W[4])  + __builtin_popcountll(b1 ^ W[5])
              + __builtin_popcountll(b2 ^ W[6])  + __builtin_popcountll(b3 ^ W[7]);
        o4.y = (float)(IN_DIM - 2 * h) * sc.y;
    }
    {
        int h = __builtin_popcountll(b0 ^ W[8])  + __builtin_popcountll(b1 ^ W[9])
              + __builtin_popcountll(b2 ^ W[10]) + __builtin_popcountll(b3 ^ W[11]);
        o4.z = (float)(IN_DIM - 2 * h) * sc.z;
    }
    {
        int h = __builtin_popcountll(b0 ^ W[12]) + __builtin_popcountll(b1 ^ W[13])
              + __builtin_popcountll(b2 ^ W[14]) + __builtin_popcountll(b3 ^ W[15]);
        o4.w = (float)(IN_DIM - 2 * h) * sc.w;
    }
    return o4;
}

__global__ void __launch_bounds__(256, 8) bin_linear(
    const float* __restrict__ x, const u64* __restrict__ wb,
    const float* __restrict__ scale, float* __restrict__ out)
{
    const int l  = threadIdx.x & 63;     // lane
    const int wv = threadIdx.x >> 6;     // wave within block (0..3)
    const int gw = blockIdx.x * 4 + wv;  // global wave id

    // Weight bits for this lane's 4 output columns (cols 4l..4l+3):
    // contiguous 16 u64 at wb[16*l] -> 4x dwordx4 loads, 32 VGPRs.
    u64 W[16];
#pragma unroll
    for (int k = 0; k < 16; ++k)
        W[k] = wb[(size_t)l * 16 + k];

    const f32x4 sc = ((const f32x4*)scale)[l];

    const int row0 = gw * ROWS_PER_WAVE;
    const f32x4* xp = (const f32x4*)(x + (size_t)row0 * IN_DIM) + l;
    f32x4*       op = (f32x4*)(out + (size_t)row0 * IN_DIM) + l;
    const int rstride = IN_DIM / 4;      // float4s per row

    // 2-deep pipeline with NAMED buffers (no arrays -> no scratch risk,
    // minimal VGPRs). Each buffer is reloaded one iteration (2 rows)
    // before its next use.
    f32x4 bufA = __builtin_nontemporal_load(&xp[0]);
    f32x4 bufB = __builtin_nontemporal_load(&xp[rstride]);

#pragma unroll 3
    for (int i = 0; i < (ROWS_PER_WAVE - 2) / 2; ++i) {   // 15 iters x 2 rows
        const int r = 2 * i;
        f32x4 c0 = bufA;
        bufA = __builtin_nontemporal_load(&xp[(r + 2) * rstride]);
        __builtin_nontemporal_store(row_dot(c0, W, sc), &op[r * rstride]);
        f32x4 c1 = bufB;
        bufB = __builtin_nontemporal_load(&xp[(r + 3) * rstride]);
        __builtin_nontemporal_store(row_dot(c1, W, sc), &op[(r + 1) * rstride]);
    }
    // tail: rows 30, 31
    __builtin_nontemporal_store(row_dot(bufA, W, sc), &op[(ROWS_PER_WAVE - 2) * rstride]);
    __builtin_nontemporal_store(row_dot(bufB, W, sc), &op[(ROWS_PER_WAVE - 1) * rstride]);
}

extern "C" void kernel_launch(void* const* d_in, const int* in_sizes, int n_in,
                              void* d_out, int out_size, void* d_ws, size_t ws_size,
                              hipStream_t stream) {
    const float* x     = (const float*)d_in[0];   // [N, 256]
    const float* wgt   = (const float*)d_in[1];   // [256, 256]
    const float* scale = (const float*)d_in[2];   // [1, 256]
    float* out = (float*)d_out;                   // [N, 256]
    u64* wb = (u64*)d_ws;                         // 256*4 u64 = 8 KB packed weight bits

    pack_weights<<<OUT_DIM, 64, 0, stream>>>(wgt, wb);
    // 2048 blocks x 4 waves = 8192 waves = 256 CU x 32 waves/CU:
    // exactly one full-residency round at 8 waves/EU, no tail round.
    bin_linear<<<N_ROWS / (4 * ROWS_PER_WAVE), 256, 0, stream>>>(x, wb, scale, out);
}